// Round 5
// baseline (115.020 us; speedup 1.0000x reference)
//
#include <hip/hip_runtime.h>

typedef _Float16 f16;
typedef f16 f16x8 __attribute__((ext_vector_type(8)));
typedef f16 f16x4 __attribute__((ext_vector_type(4)));
typedef float f32x4 __attribute__((ext_vector_type(4)));

// ---- LDS layout, 16x4-pixel tile (ty in 0..15, tx in 0..3) ----
// t01 (f16): x0 7 rows x 24 cols, stride 28 (gy in [ty*4-1, ty*4+6))
//            x1 12 rows x 44 cols, stride 48 (gy in [ty*8-2, ty*8+10))
// x2f (f32): 24 rows x 88 cols, stride 88 CONTIGUOUS (gy in [ty*16-4, ty*16+20),
//            gx in [tx*64-8, tx*64+80)); 2112 f32 used, padded to 2304 =
//            exactly 9 x 1KB global_load_lds chunks.
#define S0 28
#define S1 48
#define T0OFF 0
#define T1OFF (7 * S0)                  // 196
#define T01N  (T1OFF + 12 * S1)         // 772 f16
#define X2N   2112                      // 24*88 used f32
#define LOG2E 1.4426950408889634f

// K' = 256 layout (8 ksteps of 32):
//  kp in [0,16)   : layer0, ki=kp>>2, kj=kp&3   ; real iff ki<3 && kj<3 -> orig = 3*ki+kj
//  kp in [16,64)  : layer1, kk=kp-16, ki=kk>>3, kj=kk&7 ; real iff kj<6 -> orig = 9+6*ki+kj
//  kp in [64,256) : layer2, kk=kp-64, ki=kk>>4, kj=kk&15; real iff kj<12 -> orig = 45+12*ki+kj
//
// Fragment-major storage: fragment f = (s*4 + t)*64 + lane holds the 8 f16
// W-elements (k = s*32 + quad*8 + j, n = t*16 + ln) -> every wave load is
// 64 lanes x 16 B CONTIGUOUS (1 KB).  Serves as the *A* operand
// (operand-swapped MFMA): A[m=ln][k=quad*8+j] = W[k][chan=t*16+ln].
__global__ void prep_wt(const float* __restrict__ W, f16* __restrict__ Wt) {
  const int f = blockIdx.x * 256 + threadIdx.x;   // 0..2047
  const int s = f >> 8;
  const int t = (f >> 6) & 3;
  const int lane = f & 63;
  const int quad = lane >> 4, ln = lane & 15;
  const int n = t * 16 + ln;
  f16 vals[8];
  #pragma unroll
  for (int j = 0; j < 8; ++j) {
    int kp = s * 32 + quad * 8 + j;
    int orig = -1;
    if (kp < 16)      { int ki = kp >> 2, kj = kp & 3;                   if (ki < 3 && kj < 3) orig = 3*ki + kj; }
    else if (kp < 64) { int kk = kp - 16; int ki = kk >> 3, kj = kk & 7;  if (kj < 6)          orig = 9 + 6*ki + kj; }
    else              { int kk = kp - 64; int ki = kk >> 4, kj = kk & 15; if (kj < 12)         orig = 45 + 12*ki + kj; }
    vals[j] = (f16)((orig >= 0) ? W[orig * 64 + n] : 0.f);
  }
  *(f16x8*)(Wt + (size_t)f * 8) = *(const f16x8*)vals;
}

// async global->LDS, 16 B per lane: LDS dest = uniform base + lane*16 (HW rule),
// global src per-lane.  Zero-VGPR staging for the big x2 tile.
__device__ __forceinline__ void gload_lds16(const float* g, float* l) {
  __builtin_amdgcn_global_load_lds(
      (const __attribute__((address_space(1))) unsigned int*)g,
      (__attribute__((address_space(3))) unsigned int*)l, 16, 0, 0);
}

// barrier with LDS-only drain (used post-fixup; no vmem ordering needed there)
#define BAR_LDS() do {                                        \
    asm volatile("s_waitcnt lgkmcnt(0)" ::: "memory");        \
    __builtin_amdgcn_s_barrier();                             \
    asm volatile("" ::: "memory");                            \
  } while (0)

// Operand-swapped MFMA: D = W_frag * patch_frag, D col = lane&15 = pixel-x,
// D row = 4*quad + r = channel-in-group.  chan = 16t + 4*quad + r.
// One pixel-row per wave -> acc[4] = 16 VGPRs -> fits the 64-VGPR cap of
// __launch_bounds__(256,8): 8 blocks/CU resident, spill-free by construction.
__global__ __launch_bounds__(256, 8) void fuse_kernel(
    const float* __restrict__ x0, const float* __restrict__ x1,
    const float* __restrict__ x2, const f16* __restrict__ Wt,
    float* __restrict__ out)
{
  __shared__ __align__(16) f16   t01[T01N];
  __shared__ __align__(16) float x2f[2304];

  const int tid  = threadIdx.x;
  // bijective XCD swizzle: 4096 wgs = 8 XCDs x 512; XCD k owns images [8k, 8k+8)
  const int bid  = ((blockIdx.x & 7) << 9) | (blockIdx.x >> 3);
  const int nb   = bid >> 6;          // image (64 tiles/image)
  const int rem  = bid & 63;
  const int ty   = rem >> 2;          // 4-px tile row, 0..15
  const int tx   = rem & 3;           // 16-px tile col
  const int lane = tid & 63;
  const int wid  = tid >> 6;          // wave id == pixel row within tile
  const int ln   = lane & 15;
  const int quad = lane >> 4;

  const f16* __restrict__ wfrag = Wt + (size_t)lane * 8;
  const float* __restrict__ img2 = x2 + nb * 65536;

  // ---- x2: issue 9 x 1KB global_load_lds chunks (zero VGPRs held) ----
  // slot e = idx*256 + lane*4 ; row = e/88, col = e%88
  // src gy = ty*16-4+row, gx = tx*64-8+col (clamped; OOB zero-fixed after)
  #pragma unroll
  for (int i = 0; i < 3; ++i) {
    int idx = i * 4 + wid;            // uniform per wave
    if (idx < 9) {
      int e   = idx * 256 + lane * 4;
      int row = e / 88;
      int col = e - row * 88;
      int gy  = ty * 16 - 4 + row;
      int gx  = tx * 64 - 8 + col;
      int gyc = gy < 0 ? 0 : (gy > 255 ? 255 : gy);
      int gxc = gx < 0 ? 0 : (gx > 252 ? 252 : gx);
      gload_lds16(img2 + gyc * 256 + gxc, x2f + idx * 256);
    }
  }

  // ---- stage x1 (12 x 11 float4 = 132) and x0 (7 x 6 = 42) via VGPR path ----
  {
    const float* img = x1 + nb * 16384;
    int r  = tid / 11, c4 = tid - r * 11;
    int gy = ty * 8 - 2 + r;
    int gx = tx * 32 - 4 + 4 * c4;
    bool inb = (tid < 132) && ((unsigned)gy < 128u) && ((unsigned)gx < 128u);
    f32x4 t = inb ? *(const f32x4*)(img + gy * 128 + gx) : (f32x4){0.f, 0.f, 0.f, 0.f};
    if (tid < 132) {
      f16x4 h; h[0] = (f16)t[0]; h[1] = (f16)t[1]; h[2] = (f16)t[2]; h[3] = (f16)t[3];
      *(f16x4*)&t01[T1OFF + r * S1 + 4 * c4] = h;
    }
  }
  {
    const float* img = x0 + nb * 4096;
    int r  = tid / 6, c4 = tid - r * 6;
    int gy = ty * 4 - 1 + r;
    int gx = tx * 16 - 4 + 4 * c4;
    bool inb = (tid < 42) && ((unsigned)gy < 64u) && ((unsigned)gx < 64u);
    f32x4 t = inb ? *(const f32x4*)(img + gy * 64 + gx) : (f32x4){0.f, 0.f, 0.f, 0.f};
    if (tid < 42) {
      f16x4 h; h[0] = (f16)t[0]; h[1] = (f16)t[1]; h[2] = (f16)t[2]; h[3] = (f16)t[3];
      *(f16x4*)&t01[T0OFF + r * S0 + 4 * c4] = h;
    }
  }

  // x0 scale pixel for the epilogue (exact f32); wave's pixel row gy = ty*4+wid
  const float xs = x0[nb * 4096 + (ty * 4 + wid) * 64 + tx * 16 + ln];

  // prefetch kstep-0 weight fragments (independent of LDS)
  f16x8 bf0[4];
  #pragma unroll
  for (int t = 0; t < 4; ++t)
    bf0[t] = *(const f16x8*)(wfrag + t * 512);

  __syncthreads();   // vmcnt(0)+lgkmcnt(0) drain: x2 chunks landed, t01 ready

  // ---- border fixup: zero the OOB x2 slots (clamped loads wrote garbage) ----
  #pragma unroll
  for (int i = 0; i < 3; ++i) {
    int idx = i * 4 + wid;
    if (idx < 9) {
      int e   = idx * 256 + lane * 4;
      int row = e / 88;
      int col = e - row * 88;
      int gy  = ty * 16 - 4 + row;
      int gx  = tx * 64 - 8 + col;
      bool valid = (e < X2N) && ((unsigned)gy < 256u) && ((unsigned)gx <= 252u);
      if (!valid && e < X2N)
        *(f32x4*)&x2f[e] = (f32x4){0.f, 0.f, 0.f, 0.f};
    }
  }
  BAR_LDS();         // fixup visible to all waves

  f32x4 acc[4];
  #pragma unroll
  for (int t = 0; t < 4; ++t)
    acc[t] = (f32x4){0.f, 0.f, 0.f, 0.f};

  const int py = wid;   // this wave's pixel row within the tile

  // ---- kstep 0: quads 0,1 -> layer0 ; quads 2,3 -> layer1 ----
  {
    f16x8 a;
    if (quad < 2) {
      // layer0: ki = 2*quad + (j>>2), kj = j&3; row = py+ki, col = ln+3+kj
      const int a0 = T0OFF + (py + 2 * quad) * S0 + ln + 3;
      #pragma unroll
      for (int j = 0; j < 4; ++j) a[j]     = t01[a0 + j];
      #pragma unroll
      for (int j = 0; j < 4; ++j) a[4 + j] = t01[a0 + S0 + j];
    } else {
      // layer1: ki = quad-2, kj = j; row = 2py+ki, col = 2ln+2+kj
      const int a1 = T1OFF + (2 * py + quad - 2) * S1 + 2 * ln + 2;
      #pragma unroll
      for (int j = 0; j < 8; ++j) a[j] = t01[a1 + j];
    }
    #pragma unroll
    for (int t = 0; t < 4; ++t)
      acc[t] = __builtin_amdgcn_mfma_f32_16x16x32_f16(bf0[t], a, acc[t], 0, 0, 0);
  }
  // ---- kstep 1: all layer1, ki = 2+quad ----
  {
    f16x8 bf[4];
    #pragma unroll
    for (int t = 0; t < 4; ++t)
      bf[t] = *(const f16x8*)(wfrag + (4 + t) * 512);
    const int a1 = T1OFF + (2 * py + 2 + quad) * S1 + 2 * ln + 2;
    f16x8 a;
    #pragma unroll
    for (int j = 0; j < 8; ++j) a[j] = t01[a1 + j];
    #pragma unroll
    for (int t = 0; t < 4; ++t)
      acc[t] = __builtin_amdgcn_mfma_f32_16x16x32_f16(bf[t], a, acc[t], 0, 0, 0);
  }
  // ---- ksteps 2..7: layer2 from f32 LDS (cvt at fragment build, RTN) ----
  // row = 4py + 2(s-2) + (quad>>1), col = 4ln + 4 + 8(quad&1) + j, stride 88
  #pragma unroll 3
  for (int s = 2; s < 8; ++s) {
    f16x8 bf[4];
    #pragma unroll
    for (int t = 0; t < 4; ++t)
      bf[t] = *(const f16x8*)(wfrag + (s * 4 + t) * 512);
    const int b2 = (4 * py + 2 * (s - 2) + (quad >> 1)) * 88 + 4 * ln + 4 + 8 * (quad & 1);
    f32x4 lo = *(const f32x4*)&x2f[b2];
    f32x4 hi = *(const f32x4*)&x2f[b2 + 4];
    f16x8 a;
    #pragma unroll
    for (int j = 0; j < 4; ++j) { a[j] = (f16)lo[j]; a[4 + j] = (f16)hi[j]; }
    #pragma unroll
    for (int t = 0; t < 4; ++t)
      acc[t] = __builtin_amdgcn_mfma_f32_16x16x32_f16(bf[t], a, acc[t], 0, 0, 0);
  }

  // ---- epilogue: fully in-register softmax + direct coalesced NT stores ----
  {
    float v[4][4];
    float m = 0.f;                       // logits are post-ReLU, so >= 0
    #pragma unroll
    for (int t = 0; t < 4; ++t)
      #pragma unroll
      for (int r = 0; r < 4; ++r) {
        float x = fmaxf(acc[t][r], 0.f);
        v[t][r] = x;
        m = fmaxf(m, x);
      }
    m = fmaxf(m, __shfl_xor(m, 16));
    m = fmaxf(m, __shfl_xor(m, 32));

    float sden = 0.f;
    #pragma unroll
    for (int t = 0; t < 4; ++t)
      #pragma unroll
      for (int r = 0; r < 4; ++r) {
        float e = exp2f((v[t][r] - m) * LOG2E);
        v[t][r] = e;
        sden += e;
      }
    sden += __shfl_xor(sden, 16);
    sden += __shfl_xor(sden, 32);

    // rcp (1-ulp) instead of precise divide: absmax is f16-quantization bound.
    const float sc = xs * __builtin_amdgcn_rcpf(sden);
    const int gy = ty * 4 + wid;
    // chan = 16t + 4*quad + r -> addr = (gy*8 + 2t + (quad>>1))*512 + gx*8 + 4*(quad&1) + r
    float* op = out + nb * 262144 + (gy * 8 + (quad >> 1)) * 512
              + (tx * 16 + ln) * 8 + 4 * (quad & 1);
    #pragma unroll
    for (int t = 0; t < 4; ++t) {
      f32x4 w;
      w[0] = v[t][0] * sc; w[1] = v[t][1] * sc;
      w[2] = v[t][2] * sc; w[3] = v[t][3] * sc;
      __builtin_nontemporal_store(w, (f32x4*)(op + t * 1024));
    }
  }
}

extern "C" void kernel_launch(void* const* d_in, const int* in_sizes, int n_in,
                              void* d_out, int out_size, void* d_ws, size_t ws_size,
                              hipStream_t stream) {
  const float* x0 = (const float*)d_in[0];
  const float* x1 = (const float*)d_in[1];
  const float* x2 = (const float*)d_in[2];
  const float* W  = (const float*)d_in[3];
  float* outp     = (float*)d_out;
  f16* Wt         = (f16*)d_ws;   // 2048 fragments * 16 B = 32 KB

  prep_wt<<<dim3(8), dim3(256), 0, stream>>>(W, Wt);
  fuse_kernel<<<dim3(4096), dim3(256), 0, stream>>>(x0, x1, x2, Wt, outp);
}

// Round 6
// 106.919 us; speedup vs baseline: 1.0758x; 1.0758x over previous
//
#include <hip/hip_runtime.h>

typedef _Float16 f16;
typedef f16 f16x8 __attribute__((ext_vector_type(8)));
typedef f16 f16x4 __attribute__((ext_vector_type(4)));
typedef float f32x4 __attribute__((ext_vector_type(4)));

// ---- LDS tile strides/offsets (units: f16 elements), 16x8-pixel tile ----
// x0: 11 rows x 24 cols (gy in [ty*8-1,  ty*8+10)),  stride 28
// x1: 20 rows x 44 cols (gy in [ty*16-2, ty*16+18)), stride 48
// x2: 40 rows x 88 cols (gy in [ty*32-4, ty*32+36)), stride 92
#define S0 28
#define S1 48
#define S2 92
#define T0OFF 0
#define T1OFF (11 * S0)                 // 308
#define T2OFF (T1OFF + 20 * S1)         // 1268
#define TILEH (T2OFF + 40 * S2)         // 4948 f16 = 9896 B
#define LOG2E 1.4426950408889634f

// K' = 256 layout (8 ksteps of 32):
//  kp in [0,16)   : layer0, ki=kp>>2, kj=kp&3   ; real iff ki<3 && kj<3 -> orig = 3*ki+kj
//  kp in [16,64)  : layer1, kk=kp-16, ki=kk>>3, kj=kk&7 ; real iff kj<6 -> orig = 9+6*ki+kj
//  kp in [64,256) : layer2, kk=kp-64, ki=kk>>4, kj=kk&15; real iff kj<12 -> orig = 45+12*ki+kj
//
// Fragment-major storage: fragment f = (s*4 + t)*64 + lane holds the 8 f16
// W-elements (k = s*32 + quad*8 + j, n = t*16 + ln) -> every wave load is
// 64 lanes x 16 B CONTIGUOUS (1 KB).  Serves as the *A* operand
// (operand-swapped MFMA): A[m=ln][k=quad*8+j] = W[k][chan=t*16+ln].
__global__ void prep_wt(const float* __restrict__ W, f16* __restrict__ Wt) {
  const int f = blockIdx.x * 256 + threadIdx.x;   // 0..2047
  const int s = f >> 8;
  const int t = (f >> 6) & 3;
  const int lane = f & 63;
  const int quad = lane >> 4, ln = lane & 15;
  const int n = t * 16 + ln;
  f16 vals[8];
  #pragma unroll
  for (int j = 0; j < 8; ++j) {
    int kp = s * 32 + quad * 8 + j;
    int orig = -1;
    if (kp < 16)      { int ki = kp >> 2, kj = kp & 3;                   if (ki < 3 && kj < 3) orig = 3*ki + kj; }
    else if (kp < 64) { int kk = kp - 16; int ki = kk >> 3, kj = kk & 7;  if (kj < 6)          orig = 9 + 6*ki + kj; }
    else              { int kk = kp - 64; int ki = kk >> 4, kj = kk & 15; if (kj < 12)         orig = 45 + 12*ki + kj; }
    vals[j] = (f16)((orig >= 0) ? W[orig * 64 + n] : 0.f);
  }
  *(f16x8*)(Wt + (size_t)f * 8) = *(const f16x8*)vals;
}

// Operand-swapped MFMA: D = W_frag * patch_frag, so D col = lane&15 = pixel-x,
// D row = 4*quad + r = channel-in-group.  chan = 16t + 4*quad + r.
// Softmax over 64 channels of one pixel = 16 in-lane values + shfl_xor(16,32).
// One barrier in the whole kernel; no LDS scratch.  This round: REGULAR
// stores (through L2, write-aggregated) instead of nontemporal streaming —
// the fill kernel proves regular stores hit 6.3 TB/s at 8% occupancy.
__global__ __launch_bounds__(256, 6) void fuse_kernel(
    const float* __restrict__ x0, const float* __restrict__ x1,
    const float* __restrict__ x2, const f16* __restrict__ Wt,
    float* __restrict__ out)
{
  __shared__ __align__(16) f16 tiles[TILEH];

  const int tid  = threadIdx.x;
  // bijective XCD swizzle: 2048 wgs = 8 XCDs x 256; XCD k owns images [8k, 8k+8)
  const int bid  = ((blockIdx.x & 7) << 8) | (blockIdx.x >> 3);
  const int nb   = bid >> 5;          // image
  const int ty   = (bid >> 2) & 7;    // 8-px tile row
  const int tx   = bid & 3;           // 16-px tile col
  const int lane = tid & 63;
  const int wid  = tid >> 6;
  const int ln   = lane & 15;
  const int quad = lane >> 4;

  const f16* __restrict__ wfrag = Wt + (size_t)lane * 8;

  // ---- issue x2 loads first (biggest input, longest latency): 40 x 22 float4 = 880
  // 880 = 3*256 + 112 -> i=0..2 unconditional, i=3 predicated on tid<112.
  f32x4 v2[4];
  {
    const float* img = x2 + nb * 65536;
    #pragma unroll
    for (int i = 0; i < 4; ++i) {
      int idx = tid + 256 * i;
      int r  = idx / 22, c4 = idx - r * 22;
      int gy = ty * 32 - 4 + r;
      int gx = tx * 64 - 8 + 4 * c4;
      bool inb = (i < 3 || tid < 112) && ((unsigned)gy < 256u) && ((unsigned)gx < 256u);
      v2[i] = inb ? *(const f32x4*)(img + gy * 256 + gx) : (f32x4){0.f, 0.f, 0.f, 0.f};
    }
  }

  // ---- stage x1 (20 x 11 float4 = 220) and x0 (11 x 6 = 66) ----
  {
    const float* img = x1 + nb * 16384;
    int idx = tid;
    int r  = idx / 11, c4 = idx - r * 11;
    int gy = ty * 16 - 2 + r;
    int gx = tx * 32 - 4 + 4 * c4;
    bool inb = (idx < 220) && ((unsigned)gy < 128u) && ((unsigned)gx < 128u);
    f32x4 t = inb ? *(const f32x4*)(img + gy * 128 + gx) : (f32x4){0.f, 0.f, 0.f, 0.f};
    if (idx < 220) {
      f16x4 h; h[0] = (f16)t[0]; h[1] = (f16)t[1]; h[2] = (f16)t[2]; h[3] = (f16)t[3];
      *(f16x4*)&tiles[T1OFF + r * S1 + 4 * c4] = h;
    }
  }
  {
    const float* img = x0 + nb * 4096;
    int idx = tid;
    int r  = idx / 6, c4 = idx - r * 6;
    int gy = ty * 8 - 1 + r;
    int gx = tx * 16 - 4 + 4 * c4;
    bool inb = (idx < 66) && ((unsigned)gy < 64u) && ((unsigned)gx < 64u);
    f32x4 t = inb ? *(const f32x4*)(img + gy * 64 + gx) : (f32x4){0.f, 0.f, 0.f, 0.f};
    if (idx < 66) {
      f16x4 h; h[0] = (f16)t[0]; h[1] = (f16)t[1]; h[2] = (f16)t[2]; h[3] = (f16)t[3];
      *(f16x4*)&tiles[T0OFF + r * S0 + 4 * c4] = h;
    }
  }

  // x0 scale pixels for the epilogue (exact f32); lane's pixel is (ty*8+wid*2+cc, tx*16+ln)
  float xs[2];
  #pragma unroll
  for (int cc = 0; cc < 2; ++cc)
    xs[cc] = x0[nb * 4096 + (ty * 8 + wid * 2 + cc) * 64 + tx * 16 + ln];

  // ---- x2 -> LDS (the barrier's vmcnt(0) drain means data is here anyway) ----
  #pragma unroll
  for (int i = 0; i < 4; ++i) {
    if (i < 3 || tid < 112) {
      int idx = tid + 256 * i;
      int r  = idx / 22, c4 = idx - r * 22;
      f16x4 h; h[0] = (f16)v2[i][0]; h[1] = (f16)v2[i][1];
      h[2] = (f16)v2[i][2]; h[3] = (f16)v2[i][3];
      *(f16x4*)&tiles[T2OFF + r * S2 + 4 * c4] = h;
    }
  }

  // prefetch kstep-0 weight fragments BEFORE the barrier: independent of LDS,
  // hides their L2-hit latency under the barrier drain.  v2[] is dead here,
  // so the 16 live VGPRs don't raise the staging peak.
  f16x8 bf0[4];
  #pragma unroll
  for (int t = 0; t < 4; ++t)
    bf0[t] = *(const f16x8*)(wfrag + t * 512);

  __syncthreads();   // the ONLY barrier: all three tiles ready

  f32x4 acc[2][4];
  #pragma unroll
  for (int c = 0; c < 2; ++c)
    #pragma unroll
    for (int t = 0; t < 4; ++t)
      acc[c][t] = (f32x4){0.f, 0.f, 0.f, 0.f};

  // ---- kstep 0: quads 0,1 -> layer0 ; quads 2,3 -> layer1 ----
  {
    #pragma unroll
    for (int cc = 0; cc < 2; ++cc) {
      const int py = wid * 2 + cc;
      f16x8 a;
      if (quad < 2) {
        // layer0: ki = 2*quad + (j>>2), kj = j&3; row = py+ki, col = ln+3+kj
        const int a0 = T0OFF + (py + 2 * quad) * S0 + ln + 3;
        #pragma unroll
        for (int j = 0; j < 4; ++j) a[j]     = tiles[a0 + j];
        #pragma unroll
        for (int j = 0; j < 4; ++j) a[4 + j] = tiles[a0 + S0 + j];
      } else {
        // layer1: ki = quad-2, kj = j; row = 2py+ki, col = 2ln+2+kj
        const int a1 = T1OFF + (2 * py + quad - 2) * S1 + 2 * ln + 2;
        #pragma unroll
        for (int j = 0; j < 8; ++j) a[j] = tiles[a1 + j];
      }
      #pragma unroll
      for (int t = 0; t < 4; ++t)
        acc[cc][t] = __builtin_amdgcn_mfma_f32_16x16x32_f16(bf0[t], a, acc[cc][t], 0, 0, 0);
    }
  }
  // ---- kstep 1: all layer1, ki = 2+quad ----
  {
    f16x8 bf[4];
    #pragma unroll
    for (int t = 0; t < 4; ++t)
      bf[t] = *(const f16x8*)(wfrag + (4 + t) * 512);
    #pragma unroll
    for (int cc = 0; cc < 2; ++cc) {
      const int py = wid * 2 + cc;
      const int a1 = T1OFF + (2 * py + 2 + quad) * S1 + 2 * ln + 2;
      f16x8 a;
      #pragma unroll
      for (int j = 0; j < 8; ++j) a[j] = tiles[a1 + j];
      #pragma unroll
      for (int t = 0; t < 4; ++t)
        acc[cc][t] = __builtin_amdgcn_mfma_f32_16x16x32_f16(bf[t], a, acc[cc][t], 0, 0, 0);
    }
  }
  // ---- ksteps 2..7: layer2 ----
  // row = 4py + 2(s-2) + (quad>>1), col = 4ln + 4 + 8(quad&1) + j
  #pragma unroll 3
  for (int s = 2; s < 8; ++s) {
    f16x8 bf[4];
    #pragma unroll
    for (int t = 0; t < 4; ++t)
      bf[t] = *(const f16x8*)(wfrag + (s * 4 + t) * 512);
    #pragma unroll
    for (int cc = 0; cc < 2; ++cc) {
      const int py = wid * 2 + cc;
      const int b2 = T2OFF + (4 * py + 2 * (s - 2) + (quad >> 1)) * S2 + 4 * ln + 4 + 8 * (quad & 1);
      f16x4 lo = *(const f16x4*)&tiles[b2];
      f16x4 hi = *(const f16x4*)&tiles[b2 + 4];
      f16x8 a;
      a[0] = lo[0]; a[1] = lo[1]; a[2] = lo[2]; a[3] = lo[3];
      a[4] = hi[0]; a[5] = hi[1]; a[6] = hi[2]; a[7] = hi[3];
      #pragma unroll
      for (int t = 0; t < 4; ++t)
        acc[cc][t] = __builtin_amdgcn_mfma_f32_16x16x32_f16(bf[t], a, acc[cc][t], 0, 0, 0);
    }
  }

  // ---- epilogue: fully in-register softmax + direct coalesced stores ----
  const int gx8 = (tx * 16 + ln) * 8;
  #pragma unroll
  for (int cc = 0; cc < 2; ++cc) {
    float v[4][4];
    float m = 0.f;                       // logits are post-ReLU, so >= 0
    #pragma unroll
    for (int t = 0; t < 4; ++t)
      #pragma unroll
      for (int r = 0; r < 4; ++r) {
        float x = fmaxf(acc[cc][t][r], 0.f);
        v[t][r] = x;
        m = fmaxf(m, x);
      }
    m = fmaxf(m, __shfl_xor(m, 16));
    m = fmaxf(m, __shfl_xor(m, 32));

    float sden = 0.f;
    #pragma unroll
    for (int t = 0; t < 4; ++t)
      #pragma unroll
      for (int r = 0; r < 4; ++r) {
        float e = exp2f((v[t][r] - m) * LOG2E);
        v[t][r] = e;
        sden += e;
      }
    sden += __shfl_xor(sden, 16);
    sden += __shfl_xor(sden, 32);

    // rcp (1-ulp) instead of precise divide: absmax is f16-quantization bound.
    const float sc = xs[cc] * __builtin_amdgcn_rcpf(sden);
    const int gy = ty * 8 + wid * 2 + cc;
    // chan = 16t + 4*quad + r -> addr = (gy*8 + 2t + (quad>>1))*512 + gx*8 + 4*(quad&1) + r
    float* op = out + nb * 262144 + (gy * 8 + (quad >> 1)) * 512 + gx8 + 4 * (quad & 1);
    #pragma unroll
    for (int t = 0; t < 4; ++t) {
      f32x4 w;
      w[0] = v[t][0] * sc; w[1] = v[t][1] * sc;
      w[2] = v[t][2] * sc; w[3] = v[t][3] * sc;
      *(f32x4*)(op + t * 1024) = w;      // regular store: through L2
    }
  }
}

extern "C" void kernel_launch(void* const* d_in, const int* in_sizes, int n_in,
                              void* d_out, int out_size, void* d_ws, size_t ws_size,
                              hipStream_t stream) {
  const float* x0 = (const float*)d_in[0];
  const float* x1 = (const float*)d_in[1];
  const float* x2 = (const float*)d_in[2];
  const float* W  = (const float*)d_in[3];
  float* outp     = (float*)d_out;
  f16* Wt         = (f16*)d_ws;   // 2048 fragments * 16 B = 32 KB

  prep_wt<<<dim3(8), dim3(256), 0, stream>>>(W, Wt);
  fuse_kernel<<<dim3(2048), dim3(256), 0, stream>>>(x0, x1, x2, Wt, outp);
}